// Round 22
// baseline (107.808 us; speedup 1.0000x reference)
//
#include <hip/hip_runtime.h>

typedef __attribute__((ext_vector_type(8))) short short8;
typedef __attribute__((ext_vector_type(4))) float f32x4;
typedef __attribute__((ext_vector_type(16))) float f32x16;
typedef __attribute__((ext_vector_type(4))) unsigned u32x4;

__device__ __forceinline__ unsigned short f2bf(float f) {
  unsigned u = __builtin_bit_cast(unsigned, f);
  u += 0x7fffu + ((u >> 16) & 1u);
  return (unsigned short)(u >> 16);
}

__device__ __forceinline__ unsigned cvt_pk_bf16(float a, float b) {
  unsigned r;
  asm("v_cvt_pk_bf16_f32 %0, %1, %2" : "=v"(r) : "v"(a), "v"(b));
  return r;
}

// async global->LDS, 16B per lane; LDS dest = uniform base + lane*16
__device__ __forceinline__ void gload_lds16(const unsigned short* g, unsigned short* l) {
  __builtin_amdgcn_global_load_lds((const __attribute__((address_space(1))) unsigned int*)g,
                                   (__attribute__((address_space(3))) unsigned int*)l, 16, 0, 0);
}

// ---------------- fused convert + weight transpose (one launch) ----------------
__global__ __launch_bounds__(256) void cvt_tr(
    const float* __restrict__ q_token, const float* __restrict__ kv_token,
    const float* __restrict__ Wq, const float* __restrict__ Wkv, const float* __restrict__ Wp,
    unsigned short* __restrict__ qb, unsigned short* __restrict__ kvb,
    unsigned short* __restrict__ wqT, unsigned short* __restrict__ wkvT,
    unsigned short* __restrict__ wpT) {
  __shared__ float tile[32][33];
  const int tid = threadIdx.x;
  int bx = blockIdx.x;
  if (bx < 6144) {
    int i = bx * 256 + tid;  // 0 .. 2*786432
    const float* in = (i < 786432) ? q_token : kv_token;
    unsigned short* out = (i < 786432) ? qb : kvb;
    int j = (i < 786432) ? i : i - 786432;
    float4 v = ((const float4*)in)[j];
    ushort4 o;
    o.x = f2bf(v.x); o.y = f2bf(v.y); o.z = f2bf(v.z); o.w = f2bf(v.w);
    ((ushort4*)out)[j] = o;
    return;
  }
  bx -= 6144;
  int gx = bx % 96, gy = bx / 96;       // 96 col-tiles x 24 row-tiles
  const float* in; unsigned short* out; int C;
  if (gx < 24)       { in = Wq;  out = wqT;  C = 768;  }
  else if (gx < 72)  { in = Wkv; out = wkvT; C = 1536; gx -= 24; }
  else               { in = Wp;  out = wpT;  C = 768;  gx -= 72; }
  const int R = 768;
  int c0 = gx * 32, r0 = gy * 32;
  int tx = tid & 31, ty = tid >> 5;
  for (int i = ty; i < 32; i += 8)
    tile[i][tx] = in[(size_t)(r0 + i) * C + c0 + tx];
  __syncthreads();
  for (int i = ty; i < 32; i += 8)
    out[(size_t)(c0 + i) * R + r0 + tx] = f2bf(tile[tx][i]);
}

// ---------------- fused QKV GEMM, 128x64 tiles: y<12 -> Q proj; y>=12 -> KV proj ----------------
// K AND V stored in MFMA-FRAGMENT ORDER per head per 64-kv tile:
//   V: element (kv,d) at tile*4096 + ((s*2+hh)*64 + d)*8 + e, where p = pi(kv),
//      s=p>>4, hh=(p>>3)&1, e=p&7, pi = kv bit2<->bit3 swap (exchange-free PV).
//   K: element (kv,d) at tile*4096 + ((t4*2+hh)*64 + kv)*8 + e, t4=d>>4,
//      hh=(d>>3)&1, e=d&7 (A-fragment order: lane=kv, segment=d-slice).
__global__ __launch_bounds__(256) void gemm_qkv(
    const unsigned short* __restrict__ Aq, const unsigned short* __restrict__ Akv,
    const unsigned short* __restrict__ BtQ, const unsigned short* __restrict__ BtKV,
    unsigned short* __restrict__ Qo, unsigned short* __restrict__ Ko,
    unsigned short* __restrict__ Vo) {
  __shared__ __align__(16) unsigned short A_lds[128][64];
  __shared__ __align__(16) unsigned short B_lds[64][64];
  const bool isQ = blockIdx.y < 12;
  const unsigned short* A  = isQ ? Aq : Akv;
  const unsigned short* Bt = isQ ? BtQ : BtKV;
  const int yy = isQ ? blockIdx.y : blockIdx.y - 12;
  const int K = 768;
  const int tile_m = blockIdx.x * 128;
  const int tile_n = yy * 64;
  const int tid = threadIdx.x;
  const int wid = tid >> 6, lane = tid & 63;
  const int wm = (wid >> 1) * 64, wn = (wid & 1) * 32;
  const int lr = lane & 15, lg = lane >> 4;
  const int s_row = (lane >> 3);
  const int s_col = (lane & 7) * 8;
  f32x4 acc[4][2] = {};

  for (int k0 = 0; k0 < K; k0 += 64) {
    __syncthreads();
    // 24 chunks (A: 16, B: 8), 6 per wave; chunk = 8 rows x 64 cols = 1 KB
#pragma unroll
    for (int j = 0; j < 6; ++j) {
      const int c = wid * 6 + j;
      if (c < 16) {
        const int row = c * 8 + s_row;
        gload_lds16(&A[(size_t)(tile_m + row) * K + k0 + s_col], &A_lds[0][0] + c * 512);
      } else {
        const int row = (c - 16) * 8 + s_row;
        gload_lds16(&Bt[(size_t)(tile_n + row) * K + k0 + s_col], &B_lds[0][0] + (c - 16) * 512);
      }
    }
    __syncthreads();
    short8 a[4][2], b[2][2];
#pragma unroll
    for (int i = 0; i < 4; ++i)
#pragma unroll
      for (int t = 0; t < 2; ++t)
        a[i][t] = *(const short8*)&A_lds[wm + i * 16 + lr][t * 32 + lg * 8];
#pragma unroll
    for (int j = 0; j < 2; ++j)
#pragma unroll
      for (int t = 0; t < 2; ++t)
        b[j][t] = *(const short8*)&B_lds[wn + j * 16 + lr][t * 32 + lg * 8];
#pragma unroll
    for (int i = 0; i < 4; ++i)
#pragma unroll
      for (int j = 0; j < 2; ++j)
#pragma unroll
        for (int t = 0; t < 2; ++t)
          acc[i][j] = __builtin_amdgcn_mfma_f32_16x16x32_bf16(a[i][t], b[j][t], acc[i][j], 0, 0, 0);
  }

#pragma unroll
  for (int i = 0; i < 4; ++i)
#pragma unroll
    for (int j = 0; j < 2; ++j)
#pragma unroll
      for (int r = 0; r < 4; ++r) {
        int m = tile_m + wm + i * 16 + lg * 4 + r;
        int n = tile_n + wn + j * 16 + lr;
        float v = acc[i][j][r];
        int b = m >> 11, row = m & 2047;
        if (isQ) {
          int h = n >> 6, d = n & 63;
          Qo[((size_t)((b * 12 + h) * 2048 + row) << 6) + d] = f2bf(v);
        } else {
          int tile = row >> 6;
          if (n < 768) {
            int h = n >> 6, d = n & 63;
            // K fragment order: lane=kv within tile, segment=(d>>4)*2+((d>>3)&1)
            int kvo = row & 63;
            int t4 = d >> 4, hh = (d >> 3) & 1, ee = d & 7;
            Ko[(size_t)(b * 12 + h) * 131072 + tile * 4096 +
               ((t4 * 2 + hh) * 64 + kvo) * 8 + ee] = f2bf(v);
          } else {
            int h = (n - 768) >> 6, d = n & 63;
            // pi: swap kv bits 2<->3 within each 16-group, then fragment-order store
            int rowp = (row & ~12) | ((row & 4) << 1) | ((row & 8) >> 1);
            int poff = rowp & 63;
            int ss = poff >> 4, hh = (poff >> 3) & 1, ee = poff & 7;
            Vo[(size_t)(b * 12 + h) * 131072 + tile * 4096 +
               ((ss * 2 + hh) * 64 + d) * 8 + ee] = f2bf(v);
          }
        }
      }
}

// ---------------- proj GEMM: 64x64 tiles (grid 768 = 3 blocks/CU) ----------------
__global__ __launch_bounds__(256) void gemm_proj(
    const unsigned short* __restrict__ A, const unsigned short* __restrict__ Bt,
    float* __restrict__ outf, const float* __restrict__ bias) {
  __shared__ __align__(16) unsigned short A_lds[64][64];
  __shared__ __align__(16) unsigned short B_lds[64][64];
  const int K = 768, N = 768;
  const int tile_m = blockIdx.x * 64;
  const int tile_n = blockIdx.y * 64;
  const int tid = threadIdx.x;
  const int wid = tid >> 6, lane = tid & 63;
  const int wm = (wid >> 1) * 32, wn = (wid & 1) * 32;
  const int lr = lane & 15, lg = lane >> 4;
  const int s_r8 = lane >> 3;
  const int s_col = (lane & 7) * 8;
  f32x4 acc[2][2] = {};

  for (int k0 = 0; k0 < K; k0 += 64) {
    __syncthreads();
#pragma unroll
    for (int i = 0; i < 2; ++i) {
      const int row = (wid * 2 + i) * 8 + s_r8;
      gload_lds16(&A[(size_t)(tile_m + row) * K + k0 + s_col], &A_lds[0][0] + (wid * 2 + i) * 512);
      gload_lds16(&Bt[(size_t)(tile_n + row) * K + k0 + s_col], &B_lds[0][0] + (wid * 2 + i) * 512);
    }
    __syncthreads();
    short8 a[2][2], b[2][2];
#pragma unroll
    for (int i = 0; i < 2; ++i)
#pragma unroll
      for (int t = 0; t < 2; ++t) {
        a[i][t] = *(const short8*)&A_lds[wm + i * 16 + lr][t * 32 + lg * 8];
        b[i][t] = *(const short8*)&B_lds[wn + i * 16 + lr][t * 32 + lg * 8];
      }
#pragma unroll
    for (int i = 0; i < 2; ++i)
#pragma unroll
      for (int j = 0; j < 2; ++j)
#pragma unroll
        for (int t = 0; t < 2; ++t)
          acc[i][j] = __builtin_amdgcn_mfma_f32_16x16x32_bf16(a[i][t], b[j][t], acc[i][j], 0, 0, 0);
  }

#pragma unroll
  for (int i = 0; i < 2; ++i)
#pragma unroll
    for (int j = 0; j < 2; ++j)
#pragma unroll
      for (int r = 0; r < 4; ++r) {
        int m = tile_m + wm + i * 16 + lg * 4 + r;
        int n = tile_n + wn + j * 16 + lr;
        outf[(size_t)m * N + n] = acc[i][j][r] + bias[n];
      }
}

// ---------------- flash attention: fragment-ordered K/V, zero-barrier, K reg-dbuf ----------------
// 4 waves = 2 q-subtiles x 2 kv-halves; K and V direct global->reg (contiguous
// 512B half-wave segments). K double-buffered in regs: next tile's K issued AFTER
// the pack (S dead — low-pressure window), consumed next iter; L2 latency hides
// under pack+PV. No LDS staging, no per-iter barriers. Merge verbatim R21.
__global__ __launch_bounds__(256, 3) void attn_fwd(
    const unsigned short* __restrict__ Q, const unsigned short* __restrict__ Kb,
    const unsigned short* __restrict__ Vt, unsigned short* __restrict__ X) {
  __shared__ __align__(16) float Ob[4][32][64];   // 32 KB merge buffer
  __shared__ float m_lds[4][32];
  __shared__ float l_lds[4][64];
  const int bid = blockIdx.x;
  const int bh = bid % 24;           // bid%8 == bh%8 -> 3 heads per XCD L2
  const int q0 = (bid / 24) * 64;
  const int tid = threadIdx.x, wid = tid >> 6, lane = tid & 63;
  const int l31 = lane & 31, hi = lane >> 5;
  const int grp = wid >> 1;          // kv half
  const int qsub = wid & 1;          // q subtile
  const float Cc = 0.18033688011112042f;   // 0.125 * log2(e)
  const float THRS = 44.3614195558365f;    // 8 / Cc (defer-max threshold)

  const unsigned short* Kbase = Kb + (size_t)bh * 131072;  // fragment-ordered
  const unsigned short* Vbase = Vt + (size_t)bh * 131072;  // fragment-ordered

  // Q frags: B-operand; lane holds Q[q = q0 + qsub*32 + l31][d = t*16 + hi*8 + e]
  short8 qf[4];
  {
    const unsigned short* Qp = Q + ((size_t)bh * 2048 + q0 + qsub * 32 + l31) * 64 + hi * 8;
#pragma unroll
    for (int t = 0; t < 4; ++t) qf[t] = *(const short8*)&Qp[t * 16];
  }

  f32x16 accO0 = {}, accO1 = {};      // O^T[d = dt*32 + crow(r,hi)][q]
  float m_run = -1e30f, l_run = 0.f;  // l_run: per-half partial sum

  short8 kA[8], kB[8];
  // prologue: K tile (grp*16) -> kA
  {
    const unsigned short* Kt0 = Kbase + (grp * 16) * 4096;
#pragma unroll
    for (int s = 0; s < 4; ++s) {
      const unsigned short* kseg = Kt0 + (s * 2 + hi) * 512;
      kA[s]     = *(const short8*)&kseg[l31 * 8];
      kA[4 + s] = *(const short8*)&kseg[(32 + l31) * 8];
    }
  }

#define ATTN_ITER(KC, KN, T)                                                           \
  {                                                                                    \
    const int tile = grp * 16 + (T);                                                   \
    const unsigned short* Vtile = Vbase + tile * 4096;                                 \
    short8 vf[8];                                                                      \
    _Pragma("unroll")                                                                  \
    for (int s = 0; s < 4; ++s) {                                                      \
      const unsigned short* vseg = Vtile + (s * 2 + hi) * 512;                         \
      vf[s]     = *(const short8*)&vseg[l31 * 8];                                      \
      vf[4 + s] = *(const short8*)&vseg[(32 + l31) * 8];                               \
    }                                                                                  \
    f32x16 S0 = {}, S1 = {};                                                           \
    __builtin_amdgcn_s_setprio(1);                                                     \
    _Pragma("unroll")                                                                  \
    for (int t4 = 0; t4 < 4; ++t4) {                                                   \
      S0 = __builtin_amdgcn_mfma_f32_32x32x16_bf16(KC[t4], qf[t4], S0, 0, 0, 0);       \
      S1 = __builtin_amdgcn_mfma_f32_32x32x16_bf16(KC[4 + t4], qf[t4], S1, 0, 0, 0);   \
    }                                                                                  \
    __builtin_amdgcn_s_setprio(0);                                                     \
    float mx[8];                                                                       \
    _Pragma("unroll")                                                                  \
    for (int g = 0; g < 4; ++g) {                                                      \
      mx[g]     = fmaxf(fmaxf(S0[4 * g], S0[4 * g + 1]), fmaxf(S0[4 * g + 2], S0[4 * g + 3])); \
      mx[4 + g] = fmaxf(fmaxf(S1[4 * g], S1[4 * g + 1]), fmaxf(S1[4 * g + 2], S1[4 * g + 3])); \
    }                                                                                  \
    float rmax = fmaxf(fmaxf(fmaxf(mx[0], mx[1]), fmaxf(mx[2], mx[3])),                \
                       fmaxf(fmaxf(mx[4], mx[5]), fmaxf(mx[6], mx[7])));               \
    rmax = fmaxf(rmax, __shfl_xor(rmax, 32));                                          \
    if (!__all(rmax <= m_run + THRS)) {                                                \
      float mnew = fmaxf(m_run, rmax);                                                 \
      float alpha = exp2f((m_run - mnew) * Cc);                                        \
      m_run = mnew;                                                                    \
      l_run *= alpha;                                                                  \
      _Pragma("unroll")                                                                \
      for (int r = 0; r < 16; ++r) { accO0[r] *= alpha; accO1[r] *= alpha; }           \
    }                                                                                  \
    const float mC = m_run * Cc;                                                       \
    _Pragma("unroll")                                                                  \
    for (int r = 0; r < 16; ++r) {                                                     \
      S0[r] = exp2f(fmaf(S0[r], Cc, -mC));                                             \
      S1[r] = exp2f(fmaf(S1[r], Cc, -mC));                                             \
    }                                                                                  \
    float ts[8];                                                                       \
    _Pragma("unroll")                                                                  \
    for (int g = 0; g < 4; ++g) {                                                      \
      ts[g]     = (S0[4 * g] + S0[4 * g + 1]) + (S0[4 * g + 2] + S0[4 * g + 3]);       \
      ts[4 + g] = (S1[4 * g] + S1[4 * g + 1]) + (S1[4 * g + 2] + S1[4 * g + 3]);       \
    }                                                                                  \
    l_run += ((ts[0] + ts[1]) + (ts[2] + ts[3])) + ((ts[4] + ts[5]) + (ts[6] + ts[7])); \
    unsigned w0[8], w1[8];                                                             \
    _Pragma("unroll")                                                                  \
    for (int j = 0; j < 4; ++j) {                                                      \
      w0[j]     = cvt_pk_bf16(S0[4 * j],     S0[4 * j + 1]);                           \
      w1[j]     = cvt_pk_bf16(S0[4 * j + 2], S0[4 * j + 3]);                           \
      w0[4 + j] = cvt_pk_bf16(S1[4 * j],     S1[4 * j + 1]);                           \
      w1[4 + j] = cvt_pk_bf16(S1[4 * j + 2], S1[4 * j + 3]);                           \
    }                                                                                  \
    /* prefetch next K tile (S dead; clamped at last iter) */                          \
    {                                                                                  \
      const int tn = ((T) < 15) ? tile + 1 : tile;                                     \
      const unsigned short* Ktn = Kbase + tn * 4096;                                   \
      _Pragma("unroll")                                                                \
      for (int s = 0; s < 4; ++s) {                                                    \
        const unsigned short* kseg = Ktn + (s * 2 + hi) * 512;                         \
        KN[s]     = *(const short8*)&kseg[l31 * 8];                                    \
        KN[4 + s] = *(const short8*)&kseg[(32 + l31) * 8];                             \
      }                                                                                \
    }                                                                                  \
    __builtin_amdgcn_s_setprio(1);                                                     \
    _Pragma("unroll")                                                                  \
    for (int s = 0; s < 4; ++s) {                                                      \
      u32x4 pw = {w0[2 * s], w1[2 * s], w0[2 * s + 1], w1[2 * s + 1]};                 \
      short8 pfrag = __builtin_bit_cast(short8, pw);                                   \
      accO0 = __builtin_amdgcn_mfma_f32_32x32x16_bf16(vf[s], pfrag, accO0, 0, 0, 0);   \
      accO1 = __builtin_amdgcn_mfma_f32_32x32x16_bf16(vf[4 + s], pfrag, accO1, 0, 0, 0); \
    }                                                                                  \
    __builtin_amdgcn_s_setprio(0);                                                     \
  }

  for (int i = 0; i < 8; ++i) {
    ATTN_ITER(kA, kB, 2 * i)
    ATTN_ITER(kB, kA, 2 * i + 1)
  }
#undef ATTN_ITER

  // ---- partials -> LDS; single barrier; merge 2 kv-slices ----
#pragma unroll
  for (int dt = 0; dt < 2; ++dt) {
    const f32x16& acc = dt ? accO1 : accO0;
#pragma unroll
    for (int r = 0; r < 16; ++r)
      Ob[wid][dt * 16 + r][hi * 32 + l31] = acc[r];
  }
  if (hi == 0) m_lds[wid][l31] = m_run;
  l_lds[wid][hi * 32 + l31] = l_run;
  __syncthreads();

  {
    const int qs = wid >> 1, dh = wid & 1;
    const int sl0 = qs, sl1 = qs + 2;   // slice = wave qsub p: waves {p, p+2}
    float m0 = m_lds[sl0][l31], m1 = m_lds[sl1][l31];
    float M = fmaxf(m0, m1);
    float w0s = exp2f((m0 - M) * Cc);
    float w1s = exp2f((m1 - M) * Cc);
    float ltot = w0s * (l_lds[sl0][l31] + l_lds[sl0][32 + l31])
               + w1s * (l_lds[sl1][l31] + l_lds[sl1][32 + l31]);
    const float inv = 0.125f / ltot;  // faithful quirk: extra scale
    const int b = bh / 12, h = bh % 12;
    short8 os0, os1;
#pragma unroll
    for (int j = 0; j < 16; ++j) {
      const int d = dh * 32 + hi * 16 + j;
      const int dt = d >> 5, crow = d & 31;
      const int hs = (crow >> 2) & 1;
      const int rr = (crow & 3) | ((crow >> 3) << 2);
      float v = w0s * Ob[sl0][dt * 16 + rr][hs * 32 + l31]
              + w1s * Ob[sl1][dt * 16 + rr][hs * 32 + l31];
      if (j < 8) os0[j] = (short)f2bf(v * inv);
      else       os1[j - 8] = (short)f2bf(v * inv);
    }
    const int q = q0 + qs * 32 + l31;
    unsigned short* Xp = X + ((size_t)b * 2048 + q) * 768 + h * 64 + dh * 32 + hi * 16;
    *(short8*)Xp = os0;
    *(short8*)(Xp + 8) = os1;
  }
}

extern "C" void kernel_launch(void* const* d_in, const int* in_sizes, int n_in,
                              void* d_out, int out_size, void* d_ws, size_t ws_size,
                              hipStream_t stream) {
  const float* q_token  = (const float*)d_in[0];
  const float* kv_token = (const float*)d_in[1];
  const float* Wq    = (const float*)d_in[2];
  const float* Wkv   = (const float*)d_in[3];
  const float* Wproj = (const float*)d_in[4];
  const float* bproj = (const float*)d_in[5];
  float* out = (float*)d_out;

  unsigned short* qb   = (unsigned short*)d_ws;   // [4096][768]
  unsigned short* kvb  = qb   + 3145728;          // [4096][768]
  unsigned short* wqT  = kvb  + 3145728;          // [768][768]
  unsigned short* wkvT = wqT  + 589824;           // [1536][768]
  unsigned short* wpT  = wkvT + 1179648;          // [768][768]
  unsigned short* Qb   = wpT  + 589824;           // [B,H,Nq,D]
  unsigned short* Kbf  = Qb   + 3145728;          // [B,H,32 tiles,frag-order]
  unsigned short* Vtb  = Kbf  + 3145728;          // [B,H,32 tiles,frag-order]
  unsigned short* Xb   = Vtb  + 3145728;          // [B,Nq,C]

  cvt_tr<<<8448, 256, 0, stream>>>(q_token, kv_token, Wq, Wkv, Wproj,
                                   qb, kvb, wqT, wkvT, wpT);

  gemm_qkv<<<dim3(32, 36), 256, 0, stream>>>(qb, kvb, wqT, wkvT, Qb, Kbf, Vtb);

  attn_fwd<<<768, 256, 0, stream>>>(Qb, Kbf, Vtb, Xb);

  gemm_proj<<<dim3(64, 12), 256, 0, stream>>>(Xb, wpT, out, bproj);
}

// Round 23
// 106.053 us; speedup vs baseline: 1.0165x; 1.0165x over previous
//
#include <hip/hip_runtime.h>

typedef __attribute__((ext_vector_type(8))) short short8;
typedef __attribute__((ext_vector_type(4))) float f32x4;
typedef __attribute__((ext_vector_type(16))) float f32x16;
typedef __attribute__((ext_vector_type(4))) unsigned u32x4;

__device__ __forceinline__ unsigned short f2bf(float f) {
  unsigned u = __builtin_bit_cast(unsigned, f);
  u += 0x7fffu + ((u >> 16) & 1u);
  return (unsigned short)(u >> 16);
}

__device__ __forceinline__ unsigned cvt_pk_bf16(float a, float b) {
  unsigned r;
  asm("v_cvt_pk_bf16_f32 %0, %1, %2" : "=v"(r) : "v"(a), "v"(b));
  return r;
}

// async global->LDS, 16B per lane; LDS dest = uniform base + lane*16
__device__ __forceinline__ void gload_lds16(const unsigned short* g, unsigned short* l) {
  __builtin_amdgcn_global_load_lds((const __attribute__((address_space(1))) unsigned int*)g,
                                   (__attribute__((address_space(3))) unsigned int*)l, 16, 0, 0);
}

// ---------------- fused convert + weight transpose (one launch) ----------------
__global__ __launch_bounds__(256) void cvt_tr(
    const float* __restrict__ q_token, const float* __restrict__ kv_token,
    const float* __restrict__ Wq, const float* __restrict__ Wkv, const float* __restrict__ Wp,
    unsigned short* __restrict__ qb, unsigned short* __restrict__ kvb,
    unsigned short* __restrict__ wqT, unsigned short* __restrict__ wkvT,
    unsigned short* __restrict__ wpT) {
  __shared__ float tile[32][33];
  const int tid = threadIdx.x;
  int bx = blockIdx.x;
  if (bx < 6144) {
    int i = bx * 256 + tid;  // 0 .. 2*786432
    const float* in = (i < 786432) ? q_token : kv_token;
    unsigned short* out = (i < 786432) ? qb : kvb;
    int j = (i < 786432) ? i : i - 786432;
    float4 v = ((const float4*)in)[j];
    ushort4 o;
    o.x = f2bf(v.x); o.y = f2bf(v.y); o.z = f2bf(v.z); o.w = f2bf(v.w);
    ((ushort4*)out)[j] = o;
    return;
  }
  bx -= 6144;
  int gx = bx % 96, gy = bx / 96;       // 96 col-tiles x 24 row-tiles
  const float* in; unsigned short* out; int C;
  if (gx < 24)       { in = Wq;  out = wqT;  C = 768;  }
  else if (gx < 72)  { in = Wkv; out = wkvT; C = 1536; gx -= 24; }
  else               { in = Wp;  out = wpT;  C = 768;  gx -= 72; }
  const int R = 768;
  int c0 = gx * 32, r0 = gy * 32;
  int tx = tid & 31, ty = tid >> 5;
  for (int i = ty; i < 32; i += 8)
    tile[i][tx] = in[(size_t)(r0 + i) * C + c0 + tx];
  __syncthreads();
  for (int i = ty; i < 32; i += 8)
    out[(size_t)(c0 + i) * R + r0 + tx] = f2bf(tile[tx][i]);
}

// ---------------- fused QKV GEMM, 128x64 tiles: y<12 -> Q proj; y>=12 -> KV proj ----------------
// K AND V stored in MFMA-FRAGMENT ORDER per head per 64-kv tile:
//   V: element (kv,d) at tile*4096 + ((s*2+hh)*64 + d)*8 + e, where p = pi(kv),
//      s=p>>4, hh=(p>>3)&1, e=p&7, pi = kv bit2<->bit3 swap (exchange-free PV).
//   K: element (kv,d) at tile*4096 + ((t4*2+hh)*64 + kv)*8 + e, t4=d>>4,
//      hh=(d>>3)&1, e=d&7 (A-fragment order: lane=kv, segment=d-slice).
// Attn loads every K/V fragment as contiguous 512B half-wave segments.
__global__ __launch_bounds__(256) void gemm_qkv(
    const unsigned short* __restrict__ Aq, const unsigned short* __restrict__ Akv,
    const unsigned short* __restrict__ BtQ, const unsigned short* __restrict__ BtKV,
    unsigned short* __restrict__ Qo, unsigned short* __restrict__ Ko,
    unsigned short* __restrict__ Vo) {
  __shared__ __align__(16) unsigned short A_lds[128][64];
  __shared__ __align__(16) unsigned short B_lds[64][64];
  const bool isQ = blockIdx.y < 12;
  const unsigned short* A  = isQ ? Aq : Akv;
  const unsigned short* Bt = isQ ? BtQ : BtKV;
  const int yy = isQ ? blockIdx.y : blockIdx.y - 12;
  const int K = 768;
  const int tile_m = blockIdx.x * 128;
  const int tile_n = yy * 64;
  const int tid = threadIdx.x;
  const int wid = tid >> 6, lane = tid & 63;
  const int wm = (wid >> 1) * 64, wn = (wid & 1) * 32;
  const int lr = lane & 15, lg = lane >> 4;
  const int s_row = (lane >> 3);
  const int s_col = (lane & 7) * 8;
  f32x4 acc[4][2] = {};

  for (int k0 = 0; k0 < K; k0 += 64) {
    __syncthreads();
    // 24 chunks (A: 16, B: 8), 6 per wave; chunk = 8 rows x 64 cols = 1 KB
#pragma unroll
    for (int j = 0; j < 6; ++j) {
      const int c = wid * 6 + j;
      if (c < 16) {
        const int row = c * 8 + s_row;
        gload_lds16(&A[(size_t)(tile_m + row) * K + k0 + s_col], &A_lds[0][0] + c * 512);
      } else {
        const int row = (c - 16) * 8 + s_row;
        gload_lds16(&Bt[(size_t)(tile_n + row) * K + k0 + s_col], &B_lds[0][0] + (c - 16) * 512);
      }
    }
    __syncthreads();
    short8 a[4][2], b[2][2];
#pragma unroll
    for (int i = 0; i < 4; ++i)
#pragma unroll
      for (int t = 0; t < 2; ++t)
        a[i][t] = *(const short8*)&A_lds[wm + i * 16 + lr][t * 32 + lg * 8];
#pragma unroll
    for (int j = 0; j < 2; ++j)
#pragma unroll
      for (int t = 0; t < 2; ++t)
        b[j][t] = *(const short8*)&B_lds[wn + j * 16 + lr][t * 32 + lg * 8];
#pragma unroll
    for (int i = 0; i < 4; ++i)
#pragma unroll
      for (int j = 0; j < 2; ++j)
#pragma unroll
        for (int t = 0; t < 2; ++t)
          acc[i][j] = __builtin_amdgcn_mfma_f32_16x16x32_bf16(a[i][t], b[j][t], acc[i][j], 0, 0, 0);
  }

#pragma unroll
  for (int i = 0; i < 4; ++i)
#pragma unroll
    for (int j = 0; j < 2; ++j)
#pragma unroll
      for (int r = 0; r < 4; ++r) {
        int m = tile_m + wm + i * 16 + lg * 4 + r;
        int n = tile_n + wn + j * 16 + lr;
        float v = acc[i][j][r];
        int b = m >> 11, row = m & 2047;
        if (isQ) {
          int h = n >> 6, d = n & 63;
          Qo[((size_t)((b * 12 + h) * 2048 + row) << 6) + d] = f2bf(v);
        } else {
          int tile = row >> 6;
          if (n < 768) {
            int h = n >> 6, d = n & 63;
            // K fragment order: lane=kv within tile, segment=(d>>4)*2+((d>>3)&1)
            int kvo = row & 63;
            int t4 = d >> 4, hh = (d >> 3) & 1, ee = d & 7;
            Ko[(size_t)(b * 12 + h) * 131072 + tile * 4096 +
               ((t4 * 2 + hh) * 64 + kvo) * 8 + ee] = f2bf(v);
          } else {
            int h = (n - 768) >> 6, d = n & 63;
            // pi: swap kv bits 2<->3 within each 16-group, then fragment-order store
            int rowp = (row & ~12) | ((row & 4) << 1) | ((row & 8) >> 1);
            int poff = rowp & 63;
            int ss = poff >> 4, hh = (poff >> 3) & 1, ee = poff & 7;
            Vo[(size_t)(b * 12 + h) * 131072 + tile * 4096 +
               ((ss * 2 + hh) * 64 + d) * 8 + ee] = f2bf(v);
          }
        }
      }
}

// ---------------- proj GEMM: 64x64 tiles (grid 768 = 3 blocks/CU) ----------------
__global__ __launch_bounds__(256) void gemm_proj(
    const unsigned short* __restrict__ A, const unsigned short* __restrict__ Bt,
    float* __restrict__ outf, const float* __restrict__ bias) {
  __shared__ __align__(16) unsigned short A_lds[64][64];
  __shared__ __align__(16) unsigned short B_lds[64][64];
  const int K = 768, N = 768;
  const int tile_m = blockIdx.x * 64;
  const int tile_n = blockIdx.y * 64;
  const int tid = threadIdx.x;
  const int wid = tid >> 6, lane = tid & 63;
  const int wm = (wid >> 1) * 32, wn = (wid & 1) * 32;
  const int lr = lane & 15, lg = lane >> 4;
  const int s_r8 = lane >> 3;
  const int s_col = (lane & 7) * 8;
  f32x4 acc[2][2] = {};

  for (int k0 = 0; k0 < K; k0 += 64) {
    __syncthreads();
#pragma unroll
    for (int i = 0; i < 2; ++i) {
      const int row = (wid * 2 + i) * 8 + s_r8;
      gload_lds16(&A[(size_t)(tile_m + row) * K + k0 + s_col], &A_lds[0][0] + (wid * 2 + i) * 512);
      gload_lds16(&Bt[(size_t)(tile_n + row) * K + k0 + s_col], &B_lds[0][0] + (wid * 2 + i) * 512);
    }
    __syncthreads();
    short8 a[2][2], b[2][2];
#pragma unroll
    for (int i = 0; i < 2; ++i)
#pragma unroll
      for (int t = 0; t < 2; ++t) {
        a[i][t] = *(const short8*)&A_lds[wm + i * 16 + lr][t * 32 + lg * 8];
        b[i][t] = *(const short8*)&B_lds[wn + i * 16 + lr][t * 32 + lg * 8];
      }
#pragma unroll
    for (int i = 0; i < 2; ++i)
#pragma unroll
      for (int j = 0; j < 2; ++j)
#pragma unroll
        for (int t = 0; t < 2; ++t)
          acc[i][j] = __builtin_amdgcn_mfma_f32_16x16x32_bf16(a[i][t], b[j][t], acc[i][j], 0, 0, 0);
  }

#pragma unroll
  for (int i = 0; i < 2; ++i)
#pragma unroll
    for (int j = 0; j < 2; ++j)
#pragma unroll
      for (int r = 0; r < 4; ++r) {
        int m = tile_m + wm + i * 16 + lg * 4 + r;
        int n = tile_n + wn + j * 16 + lr;
        outf[(size_t)m * N + n] = acc[i][j][r] + bias[n];
      }
}

// ---------------- flash attention: R21 VERBATIM (verified 52.0 us) ----------------
// 4 waves = 2 q-subtiles x 2 kv-halves; K and V both direct global->reg from
// fragment-ordered layouts (contiguous 512B half-wave segments, L2-resident).
// No LDS staging, no per-iter barriers — waves free-run (setprio pays here).
// R22's K reg-dbuf was neutral (TLP already covers K latency; +2.3MB FETCH).
__global__ __launch_bounds__(256, 3) void attn_fwd(
    const unsigned short* __restrict__ Q, const unsigned short* __restrict__ Kb,
    const unsigned short* __restrict__ Vt, unsigned short* __restrict__ X) {
  __shared__ __align__(16) float Ob[4][32][64];   // 32 KB merge buffer
  __shared__ float m_lds[4][32];
  __shared__ float l_lds[4][64];
  const int bid = blockIdx.x;
  const int bh = bid % 24;           // bid%8 == bh%8 -> 3 heads per XCD L2
  const int q0 = (bid / 24) * 64;
  const int tid = threadIdx.x, wid = tid >> 6, lane = tid & 63;
  const int l31 = lane & 31, hi = lane >> 5;
  const int grp = wid >> 1;          // kv half
  const int qsub = wid & 1;          // q subtile
  const float Cc = 0.18033688011112042f;   // 0.125 * log2(e)
  const float THRS = 44.3614195558365f;    // 8 / Cc (defer-max threshold)

  const unsigned short* Kbase = Kb + (size_t)bh * 131072;  // fragment-ordered
  const unsigned short* Vbase = Vt + (size_t)bh * 131072;  // fragment-ordered

  // Q frags: B-operand; lane holds Q[q = q0 + qsub*32 + l31][d = t*16 + hi*8 + e]
  short8 qf[4];
  {
    const unsigned short* Qp = Q + ((size_t)bh * 2048 + q0 + qsub * 32 + l31) * 64 + hi * 8;
#pragma unroll
    for (int t = 0; t < 4; ++t) qf[t] = *(const short8*)&Qp[t * 16];
  }

  f32x16 accO0 = {}, accO1 = {};      // O^T[d = dt*32 + crow(r,hi)][q]
  float m_run = -1e30f, l_run = 0.f;  // l_run: per-half partial sum

  for (int t = 0; t < 16; ++t) {
    const int tile = grp * 16 + t;    // 64-kv tile index
    const unsigned short* Ktile = Kbase + tile * 4096;
    const unsigned short* Vtile = Vbase + tile * 4096;
    // K and V fragment loads: contiguous half-wave segments (L2-resident)
    short8 kA[8], vf[8];
#pragma unroll
    for (int s = 0; s < 4; ++s) {
      const unsigned short* kseg = Ktile + (s * 2 + hi) * 512;
      kA[s]     = *(const short8*)&kseg[l31 * 8];
      kA[4 + s] = *(const short8*)&kseg[(32 + l31) * 8];
      const unsigned short* vseg = Vtile + (s * 2 + hi) * 512;
      vf[s]     = *(const short8*)&vseg[l31 * 8];
      vf[4 + s] = *(const short8*)&vseg[(32 + l31) * 8];
    }
    // ---- QK^T (swapped) ----
    f32x16 S0 = {}, S1 = {};
    __builtin_amdgcn_s_setprio(1);
#pragma unroll
    for (int t4 = 0; t4 < 4; ++t4) {
      S0 = __builtin_amdgcn_mfma_f32_32x32x16_bf16(kA[t4], qf[t4], S0, 0, 0, 0);
      S1 = __builtin_amdgcn_mfma_f32_32x32x16_bf16(kA[4 + t4], qf[t4], S1, 0, 0, 0);
    }
    __builtin_amdgcn_s_setprio(0);
    // ---- online softmax: tree rmax ----
    float mx[8];
#pragma unroll
    for (int g = 0; g < 4; ++g) {
      mx[g]     = fmaxf(fmaxf(S0[4 * g], S0[4 * g + 1]), fmaxf(S0[4 * g + 2], S0[4 * g + 3]));
      mx[4 + g] = fmaxf(fmaxf(S1[4 * g], S1[4 * g + 1]), fmaxf(S1[4 * g + 2], S1[4 * g + 3]));
    }
    float rmax = fmaxf(fmaxf(fmaxf(mx[0], mx[1]), fmaxf(mx[2], mx[3])),
                       fmaxf(fmaxf(mx[4], mx[5]), fmaxf(mx[6], mx[7])));
    rmax = fmaxf(rmax, __shfl_xor(rmax, 32));
    if (!__all(rmax <= m_run + THRS)) {
      float mnew = fmaxf(m_run, rmax);
      float alpha = exp2f((m_run - mnew) * Cc);
      m_run = mnew;
      l_run *= alpha;
#pragma unroll
      for (int r = 0; r < 16; ++r) { accO0[r] *= alpha; accO1[r] *= alpha; }
    }
    const float mC = m_run * Cc;
#pragma unroll
    for (int r = 0; r < 16; ++r) {
      S0[r] = exp2f(fmaf(S0[r], Cc, -mC));
      S1[r] = exp2f(fmaf(S1[r], Cc, -mC));
    }
    float ts[8];
#pragma unroll
    for (int g = 0; g < 4; ++g) {
      ts[g]     = (S0[4 * g] + S0[4 * g + 1]) + (S0[4 * g + 2] + S0[4 * g + 3]);
      ts[4 + g] = (S1[4 * g] + S1[4 * g + 1]) + (S1[4 * g + 2] + S1[4 * g + 3]);
    }
    l_run += ((ts[0] + ts[1]) + (ts[2] + ts[3])) + ((ts[4] + ts[5]) + (ts[6] + ts[7]));
    // ---- pack P to bf16 (verified) ----
    unsigned w0[8], w1[8];
#pragma unroll
    for (int j = 0; j < 4; ++j) {
      w0[j]     = cvt_pk_bf16(S0[4 * j],     S0[4 * j + 1]);
      w1[j]     = cvt_pk_bf16(S0[4 * j + 2], S0[4 * j + 3]);
      w0[4 + j] = cvt_pk_bf16(S1[4 * j],     S1[4 * j + 1]);
      w1[4 + j] = cvt_pk_bf16(S1[4 * j + 2], S1[4 * j + 3]);
    }
    // ---- PV: exchange-free (pi baked into V layout) ----
    __builtin_amdgcn_s_setprio(1);
#pragma unroll
    for (int s = 0; s < 4; ++s) {
      u32x4 pw = {w0[2 * s], w1[2 * s], w0[2 * s + 1], w1[2 * s + 1]};
      short8 pfrag = __builtin_bit_cast(short8, pw);
      accO0 = __builtin_amdgcn_mfma_f32_32x32x16_bf16(vf[s], pfrag, accO0, 0, 0, 0);
      accO1 = __builtin_amdgcn_mfma_f32_32x32x16_bf16(vf[4 + s], pfrag, accO1, 0, 0, 0);
    }
    __builtin_amdgcn_s_setprio(0);
  }

  // ---- partials -> LDS; single barrier; merge 2 kv-slices ----
#pragma unroll
  for (int dt = 0; dt < 2; ++dt) {
    const f32x16& acc = dt ? accO1 : accO0;
#pragma unroll
    for (int r = 0; r < 16; ++r)
      Ob[wid][dt * 16 + r][hi * 32 + l31] = acc[r];
  }
  if (hi == 0) m_lds[wid][l31] = m_run;
  l_lds[wid][hi * 32 + l31] = l_run;
  __syncthreads();

  {
    const int qs = wid >> 1, dh = wid & 1;
    const int sl0 = qs, sl1 = qs + 2;   // slice = wave qsub p: waves {p, p+2}
    float m0 = m_lds[sl0][l31], m1 = m_lds[sl1][l31];
    float M = fmaxf(m0, m1);
    float w0s = exp2f((m0 - M) * Cc);
    float w1s = exp2f((m1 - M) * Cc);
    float ltot = w0s * (l_lds[sl0][l31] + l_lds[sl0][32 + l31])
               + w1s * (l_lds[sl1][l31] + l_lds[sl1][32 + l31]);
    const float inv = 0.125f / ltot;  // faithful quirk: extra scale
    const int b = bh / 12, h = bh % 12;
    short8 os0, os1;
#pragma unroll
    for (int j = 0; j < 16; ++j) {
      const int d = dh * 32 + hi * 16 + j;
      const int dt = d >> 5, crow = d & 31;
      const int hs = (crow >> 2) & 1;
      const int rr = (crow & 3) | ((crow >> 3) << 2);
      float v = w0s * Ob[sl0][dt * 16 + rr][hs * 32 + l31]
              + w1s * Ob[sl1][dt * 16 + rr][hs * 32 + l31];
      if (j < 8) os0[j] = (short)f2bf(v * inv);
      else       os1[j - 8] = (short)f2bf(v * inv);
    }
    const int q = q0 + qs * 32 + l31;
    unsigned short* Xp = X + ((size_t)b * 2048 + q) * 768 + h * 64 + dh * 32 + hi * 16;
    *(short8*)Xp = os0;
    *(short8*)(Xp + 8) = os1;
  }
}

extern "C" void kernel_launch(void* const* d_in, const int* in_sizes, int n_in,
                              void* d_out, int out_size, void* d_ws, size_t ws_size,
                              hipStream_t stream) {
  const float* q_token  = (const float*)d_in[0];
  const float* kv_token = (const float*)d_in[1];
  const float* Wq    = (const float*)d_in[2];
  const float* Wkv   = (const float*)d_in[3];
  const float* Wproj = (const float*)d_in[4];
  const float* bproj = (const float*)d_in[5];
  float* out = (float*)d_out;

  unsigned short* qb   = (unsigned short*)d_ws;   // [4096][768]
  unsigned short* kvb  = qb   + 3145728;          // [4096][768]
  unsigned short* wqT  = kvb  + 3145728;          // [768][768]
  unsigned short* wkvT = wqT  + 589824;           // [1536][768]
  unsigned short* wpT  = wkvT + 1179648;          // [768][768]
  unsigned short* Qb   = wpT  + 589824;           // [B,H,Nq,D]
  unsigned short* Kbf  = Qb   + 3145728;          // [B,H,32 tiles,frag-order]
  unsigned short* Vtb  = Kbf  + 3145728;          // [B,H,32 tiles,frag-order]
  unsigned short* Xb   = Vtb  + 3145728;          // [B,Nq,C]

  cvt_tr<<<8448, 256, 0, stream>>>(q_token, kv_token, Wq, Wkv, Wproj,
                                   qb, kvb, wqT, wkvT, wpT);

  gemm_qkv<<<dim3(32, 36), 256, 0, stream>>>(qb, kvb, wqT, wkvT, Qb, Kbf, Vtb);

  attn_fwd<<<768, 256, 0, stream>>>(Qb, Kbf, Vtb, Xb);

  gemm_proj<<<dim3(64, 12), 256, 0, stream>>>(Xb, wpT, out, bproj);
}